// Round 3
// baseline (11142.307 us; speedup 1.0000x reference)
//
#include <hip/hip_runtime.h>
#include <math.h>

// ---------------------------------------------------------------------------
// Persistent 2-layer LSTM via MFMA split-bf16 (hi+lo, 3-term) fp32 emulation.
// 208 blocks x 512 thr (1/CU). Pipeline: A(64)=layer0 s=t | B(128)=layer1
// s=t-1 | C(16)=proj s=t-2. R4 flag barrier.
// R9: decoupled counted-vmcnt schedule. Per phase: commit-wait retires ONLY
// the staged h quarter (2-phase slack), LDS write, raw barrier, then a
// separate weight-wait (2-phase slack) before the MFMAs. All in-loop VMEM is
// inline asm (A's kl4-7 now prefetched too -> no compiler/asm vmcnt alias).
// Queue-simulated literals: A commit 36/16, wwait 24/20/0; B commit 20/8,
// wwait 16/12/0; C commit 12/4, wwait 12/8/0.
// ---------------------------------------------------------------------------

typedef __attribute__((ext_vector_type(8))) short short8;
typedef __attribute__((ext_vector_type(4))) float f32x4;

constexpr int kV = 256, kH = 1024, kB = 32, kS = 512, G4H = 4096;
constexpr int NT = 512, NBLK = 208;
constexpr int NA = 64, B0 = 64, C0 = 192, ROOT = NBLK - 1;

// ws layout in SHORT units
constexpr long SZW = 4194304L;            // shorts per packed 1024x4096 matrix
constexpr long SZY = 262144L;             // shorts per packed Why array
constexpr long WP0H = 0,        WP0L = SZW;
constexpr long WP1XH = 2*SZW,   WP1XL = 3*SZW;
constexpr long WP1HH = 4*SZW,   WP1HL = 5*SZW;
constexpr long WYH  = 6*SZW,    WYL  = 6*SZW + SZY;
constexpr long HOFF = 6*SZW + 2*SZY;      // h arrays: h0h[2][32K],h0l,h1h,h1l

#define MFMA(a,b,c) __builtin_amdgcn_mfma_f32_16x16x32_bf16(a, b, c, 0, 0, 0)

// counted vmcnt wait + scheduler fence (rule: sched_barrier after asm waits)
#define VM_WAIT(n) do { \
    asm volatile("s_waitcnt vmcnt(" #n ")" ::: "memory"); \
    __builtin_amdgcn_sched_barrier(0); \
  } while (0)

__device__ __forceinline__ float sigmoidf_(float v) { return 1.f / (1.f + expf(-v)); }

__device__ __forceinline__ void bf16split(float w, unsigned& hi, unsigned& lo) {
  unsigned u = __float_as_uint(w);
  unsigned r = (u + 0x7fffu + ((u >> 16) & 1u)) >> 16;
  float res = w - __uint_as_float(r << 16);
  unsigned u2 = __float_as_uint(res);
  unsigned r2 = (u2 + 0x7fffu + ((u2 >> 16) & 1u)) >> 16;
  hi = r; lo = r2;
}

// ---------------- coherent (cache-bypass) helpers --------------------------

__device__ __forceinline__ void coh_store_u32(unsigned* p, unsigned v) {
  asm volatile("global_store_dword %0, %1, off sc0 sc1" :: "v"(p), "v"(v) : "memory");
}
__device__ __forceinline__ void coh_store_u16(unsigned short* p, unsigned v) {
  asm volatile("global_store_short %0, %1, off sc0 sc1" :: "v"(p), "v"(v) : "memory");
}
__device__ __forceinline__ unsigned coh_load_u32(const unsigned* p) {
  unsigned v;
  asm volatile("global_load_dword %0, %1, off sc0 sc1\n\ts_waitcnt vmcnt(0)"
               : "=v"(v) : "v"(p) : "memory");
  return v;
}

// ---------------- async staging: issue / write -----------------------------

// issue one 256-k quarter of h (hi+lo): 4 coherent 16B loads, NO wait.
__device__ __forceinline__ void stage_issue(const unsigned short* gH,
                                            const unsigned short* gL,
                                            int qtr, int tid,
                                            float4& a, float4& b, float4& c, float4& d) {
  const int b0_ = tid >> 5, kg = tid & 31, b1_ = b0_ + 16;
  const unsigned short* p0 = gH + b0_ * 1024 + qtr * 256 + kg * 8;
  const unsigned short* p1 = gH + b1_ * 1024 + qtr * 256 + kg * 8;
  const unsigned short* p2 = gL + b0_ * 1024 + qtr * 256 + kg * 8;
  const unsigned short* p3 = gL + b1_ * 1024 + qtr * 256 + kg * 8;
  asm volatile(
      "global_load_dwordx4 %0, %4, off sc0 sc1\n\t"
      "global_load_dwordx4 %1, %5, off sc0 sc1\n\t"
      "global_load_dwordx4 %2, %6, off sc0 sc1\n\t"
      "global_load_dwordx4 %3, %7, off sc0 sc1"
      : "=&v"(a), "=&v"(b), "=&v"(c), "=&v"(d)
      : "v"(p0), "v"(p1), "v"(p2), "v"(p3) : "memory");
}

// LDS write of a committed quarter (caller has already done the vmcnt wait)
__device__ __forceinline__ void stage_write(short8* HH, short8* HL, int tid,
                                            const float4& a, const float4& b,
                                            const float4& c, const float4& d) {
  const int b0_ = tid >> 5, kg = tid & 31, b1_ = b0_ + 16;
  HH[b0_ * 33 + kg] = __builtin_bit_cast(short8, a);
  HH[b1_ * 33 + kg] = __builtin_bit_cast(short8, b);
  HL[b0_ * 33 + kg] = __builtin_bit_cast(short8, c);
  HL[b1_ * 33 + kg] = __builtin_bit_cast(short8, d);
}

// weight prefetch: 4 consecutive kk fragments, hi+lo (8x16B), NO wait
__device__ __forceinline__ void wiss4(const short8* bh_, const short8* bl_,
                                      int kk0, int strd,
                                      float4& h0_, float4& h1_, float4& h2_, float4& h3_,
                                      float4& l0_, float4& l1_, float4& l2_, float4& l3_) {
  const short8* a0 = bh_ + (long)(kk0 + 0) * strd;
  const short8* a1 = bh_ + (long)(kk0 + 1) * strd;
  const short8* a2 = bh_ + (long)(kk0 + 2) * strd;
  const short8* a3 = bh_ + (long)(kk0 + 3) * strd;
  const short8* c0 = bl_ + (long)(kk0 + 0) * strd;
  const short8* c1 = bl_ + (long)(kk0 + 1) * strd;
  const short8* c2 = bl_ + (long)(kk0 + 2) * strd;
  const short8* c3 = bl_ + (long)(kk0 + 3) * strd;
  asm volatile(
      "global_load_dwordx4 %0, %8, off\n\t"
      "global_load_dwordx4 %1, %9, off\n\t"
      "global_load_dwordx4 %2, %10, off\n\t"
      "global_load_dwordx4 %3, %11, off\n\t"
      "global_load_dwordx4 %4, %12, off\n\t"
      "global_load_dwordx4 %5, %13, off\n\t"
      "global_load_dwordx4 %6, %14, off\n\t"
      "global_load_dwordx4 %7, %15, off"
      : "=&v"(h0_), "=&v"(h1_), "=&v"(h2_), "=&v"(h3_),
        "=&v"(l0_), "=&v"(l1_), "=&v"(l2_), "=&v"(l3_)
      : "v"(a0), "v"(a1), "v"(a2), "v"(a3),
        "v"(c0), "v"(c1), "v"(c2), "v"(c3) : "memory");
}

// weight prefetch: 2 consecutive kk fragments, hi+lo (4x16B), NO wait (C)
__device__ __forceinline__ void wiss2(const short8* bh_, const short8* bl_,
                                      int kk0, int strd,
                                      float4& h0_, float4& h1_,
                                      float4& l0_, float4& l1_) {
  const short8* a0 = bh_ + (long)(kk0 + 0) * strd;
  const short8* a1 = bh_ + (long)(kk0 + 1) * strd;
  const short8* c0 = bl_ + (long)(kk0 + 0) * strd;
  const short8* c1 = bl_ + (long)(kk0 + 1) * strd;
  asm volatile(
      "global_load_dwordx4 %0, %4, off\n\t"
      "global_load_dwordx4 %1, %5, off\n\t"
      "global_load_dwordx4 %2, %6, off\n\t"
      "global_load_dwordx4 %3, %7, off"
      : "=&v"(h0_), "=&v"(h1_), "=&v"(l0_), "=&v"(l1_)
      : "v"(a0), "v"(a1), "v"(c0), "v"(c1) : "memory");
}

// barrier that does NOT drain vmcnt: only LDS ops, then raw s_barrier.
__device__ __forceinline__ void lds_barrier() {
  asm volatile("s_waitcnt lgkmcnt(0)" ::: "memory");
  __builtin_amdgcn_sched_barrier(0);
  __builtin_amdgcn_s_barrier();
  __builtin_amdgcn_sched_barrier(0);
}

// -------------------------- prep kernels -----------------------------------

__global__ void pack_w(const float* __restrict__ in, unsigned short* __restrict__ hi,
                       unsigned short* __restrict__ lo, int ncols) {
  int id = blockIdx.x * 256 + threadIdx.x;
  int slab = id / ncols, row = id % ncols;   // slab < 128
  int k0 = (slab >> 2) * 32 + (slab & 3) * 8;
  long ob = ((long)slab * ncols + row) * 8;
  #pragma unroll
  for (int e = 0; e < 8; ++e) {
    float w = in[(long)(k0 + e) * ncols + row];
    unsigned h_, l_;
    bf16split(w, h_, l_);
    hi[ob + e] = (unsigned short)h_;
    lo[ob + e] = (unsigned short)l_;
  }
}

__global__ void zero_state(unsigned* __restrict__ p, int n) {
  int i = blockIdx.x * 256 + threadIdx.x;
  if (i < n) p[i] = 0u;
}

// -------------------------- main persistent kernel -------------------------

extern "C" __global__ void __launch_bounds__(512, 1)
lstm_persist(const int* __restrict__ x,
             const float* __restrict__ Wx0,
             const float* __restrict__ b0v,
             const float* __restrict__ b1v,
             const float* __restrict__ byv,
             unsigned short* __restrict__ wss,
             float* __restrict__ out) {
  const short8* wp0h  = (const short8*)(wss + WP0H);
  const short8* wp0l  = (const short8*)(wss + WP0L);
  const short8* wp1xh = (const short8*)(wss + WP1XH);
  const short8* wp1xl = (const short8*)(wss + WP1XL);
  const short8* wp1hh = (const short8*)(wss + WP1HH);
  const short8* wp1hl = (const short8*)(wss + WP1HL);
  const short8* wyh   = (const short8*)(wss + WYH);
  const short8* wyl   = (const short8*)(wss + WYL);
  unsigned short* h0h = wss + HOFF;            // [2][32][1024]
  unsigned short* h0l = h0h + 65536;
  unsigned short* h1h = h0h + 131072;
  unsigned short* h1l = h0h + 196608;
  unsigned* arrive = (unsigned*)(h0h + 262144);  // stride-16 flags
  unsigned* gen = arrive + 4096;

  const int tid = threadIdx.x, blk = blockIdx.x;
  const int lane = tid & 63, m = lane & 15, quad = lane >> 4, w = tid >> 6;

  __shared__ short8 HSH[2][32 * 33];   // 2 x 16.5 KB  h hi quarter (dbuf)
  __shared__ short8 HSL[2][32 * 33];   // 2 x 16.5 KB  h lo quarter (dbuf)
  __shared__ float gx[2048];           // 8 KB gate/output exchange

  float c0r = 0.f, c1r = 0.f;

  // ---- loop-invariant bias loads (hoisted out of the t-loop) --------------
  float bA0 = 0.f, bA1 = 0.f, bA2 = 0.f, bA3 = 0.f;
  float bB0 = 0.f, bB1 = 0.f, bB2 = 0.f, bB3 = 0.f;
  float byr = 0.f;
  if (blk < NA) {
    const int u = tid >> 5, j2e = blk * 16 + u;
    bA0 = b0v[j2e];            bA1 = b0v[kH + j2e];
    bA2 = b0v[2 * kH + j2e];   bA3 = b0v[3 * kH + j2e];
  } else if (blk < C0) {
    if (tid < 256) {
      const int u = tid >> 5, j2e = (blk - B0) * 8 + u;
      bB0 = b1v[j2e];          bB1 = b1v[kH + j2e];
      bB2 = b1v[2 * kH + j2e]; bB3 = b1v[3 * kH + j2e];
    }
  } else {
    byr = byv[(blk - C0) * 16 + (tid & 15)];
  }

  #pragma unroll 1
  for (int t = 0; t < kS + 2; ++t) {
    if (blk < NA) {
      // ---------------- A: layer0 cell, s = t ---------------------------
      const int s = t;
      if (s < kS) {
        const int g = w >> 1, nt = w & 1, j0A = blk * 16;
        const int bcol = nt * 16 + m;
        const short8* aph = wp0h + quad * 4096 + (g * 1024 + j0A + m);
        const short8* apl = wp0l + quad * 4096 + (g * 1024 + j0A + m);
        const int rpar = (s + 1) & 1;
        const unsigned short* gH = h0h + rpar * 32768;
        const unsigned short* gL = h0l + rpar * 32768;
        f32x4 acc = {0.f, 0.f, 0.f, 0.f};
        float4 sr[2][4];
        float4 wph[2][8], wpl[2][8];
        // compiler x-load first (its own wait precedes any asm issue)
        const int ue = tid >> 5, be = tid & 31;
        const int j2e = j0A + ue;
        const int xs = x[be * kS + s];
        const float* wxp = Wx0 + (long)xs * G4H + j2e;
        float wxi, wxf, wxg, wxo;
        asm volatile(
            "global_load_dword %0, %4, off\n\t"
            "global_load_dword %1, %5, off\n\t"
            "global_load_dword %2, %6, off\n\t"
            "global_load_dword %3, %7, off"
            : "=&v"(wxi), "=&v"(wxf), "=&v"(wxg), "=&v"(wxo)
            : "v"(wxp), "v"(wxp + kH), "v"(wxp + 2 * kH), "v"(wxp + 3 * kH)
            : "memory");
        // prologue queue: [wx4, s0, w0(16), s1, w1(16)]
        stage_issue(gH, gL, 0, tid, sr[0][0], sr[0][1], sr[0][2], sr[0][3]);
        wiss4(aph, apl, 0, 16384,
              wph[0][0], wph[0][1], wph[0][2], wph[0][3],
              wpl[0][0], wpl[0][1], wpl[0][2], wpl[0][3]);
        wiss4(aph, apl, 4, 16384,
              wph[0][4], wph[0][5], wph[0][6], wph[0][7],
              wpl[0][4], wpl[0][5], wpl[0][6], wpl[0][7]);
        stage_issue(gH, gL, 1, tid, sr[1][0], sr[1][1], sr[1][2], sr[1][3]);
        wiss4(aph, apl, 8, 16384,
              wph[1][0], wph[1][1], wph[1][2], wph[1][3],
              wpl[1][0], wpl[1][1], wpl[1][2], wpl[1][3]);
        wiss4(aph, apl, 12, 16384,
              wph[1][4], wph[1][5], wph[1][6], wph[1][7],
              wpl[1][4], wpl[1][5], wpl[1][6], wpl[1][7]);
        #pragma unroll
        for (int q = 0; q < 4; ++q) {
          if (q < 3) { VM_WAIT(36); } else { VM_WAIT(16); }
          stage_write(&HSH[q & 1][0], &HSL[q & 1][0], tid,
                      sr[q & 1][0], sr[q & 1][1], sr[q & 1][2], sr[q & 1][3]);
          lds_barrier();
          if (q < 2)
            stage_issue(gH, gL, q + 2, tid,
                        sr[q & 1][0], sr[q & 1][1], sr[q & 1][2], sr[q & 1][3]);
          if (q < 2)      { VM_WAIT(24); }
          else if (q == 2){ VM_WAIT(20); }
          else            { VM_WAIT(0);  }
          #pragma unroll
          for (int kl = 0; kl < 8; ++kl) {
            short8 ah = __builtin_bit_cast(short8, wph[q & 1][kl]);
            short8 al = __builtin_bit_cast(short8, wpl[q & 1][kl]);
            short8 bh = HSH[q & 1][bcol * 33 + kl * 4 + quad];
            short8 bl = HSL[q & 1][bcol * 33 + kl * 4 + quad];
            acc = MFMA(ah, bh, acc);
            acc = MFMA(ah, bl, acc);
            acc = MFMA(al, bh, acc);
          }
          if (q < 2) {   // weights for phase q+2 into the set just consumed
            wiss4(aph, apl, (q + 2) * 8, 16384,
                  wph[q & 1][0], wph[q & 1][1], wph[q & 1][2], wph[q & 1][3],
                  wpl[q & 1][0], wpl[q & 1][1], wpl[q & 1][2], wpl[q & 1][3]);
            wiss4(aph, apl, (q + 2) * 8 + 4, 16384,
                  wph[q & 1][4], wph[q & 1][5], wph[q & 1][6], wph[q & 1][7],
                  wpl[q & 1][4], wpl[q & 1][5], wpl[q & 1][6], wpl[q & 1][7]);
          }
        }
        #pragma unroll
        for (int r = 0; r < 4; ++r)
          gx[(g * 16 + quad * 4 + r) * 32 + bcol] = acc[r];
        lds_barrier();
        {
          float gi = gx[(0 * 16 + ue) * 32 + be] + wxi + bA0;
          float gf = gx[(1 * 16 + ue) * 32 + be] + wxf + bA1;
          float gg = gx[(2 * 16 + ue) * 32 + be] + wxg + bA2;
          float go = gx[(3 * 16 + ue) * 32 + be] + wxo + bA3;
          float cc = sigmoidf_(gf) * c0r + sigmoidf_(gi) * tanhf(gg);
          float hh = sigmoidf_(go) * tanhf(cc);
          c0r = cc;
          unsigned h_, l_;
          bf16split(hh, h_, l_);
          const int wpar = s & 1;
          coh_store_u16(h0h + wpar * 32768 + be * 1024 + j2e, h_);
          coh_store_u16(h0l + wpar * 32768 + be * 1024 + j2e, l_);
        }
      }
    } else if (blk < C0) {
      // ---------------- B: layer1 cell, s = t-1 -------------------------
      const int s = t - 1;
      if (s >= 0 && s < kS) {
        const int kq = w >> 2, mt = (w >> 1) & 1, nt = w & 1;
        const int rowB = mt * 16 + m;
        const int gB = rowB >> 3, uB = rowB & 7;
        const int growB = gB * 1024 + (blk - B0) * 8 + uB;
        const int bcol = nt * 16 + m;
        const short8* axh = wp1xh + quad * 4096 + growB;
        const short8* axl = wp1xl + quad * 4096 + growB;
        const short8* ahh = wp1hh + quad * 4096 + growB;
        const short8* ahl = wp1hl + quad * 4096 + growB;
        const unsigned short* gH0 = h0h + (s & 1) * 32768;
        const unsigned short* gL0 = h0l + (s & 1) * 32768;
        const unsigned short* gH1 = h1h + ((s + 1) & 1) * 32768;
        const unsigned short* gL1 = h1l + ((s + 1) & 1) * 32768;
        f32x4 acc = {0.f, 0.f, 0.f, 0.f};
        float4 sr[2][4];
        float4 wph[2][4], wpl[2][4];
        // prologue queue: [s0, w0(8), s1, w1(8)]
        stage_issue(gH0, gL0, 0, tid, sr[0][0], sr[0][1], sr[0][2], sr[0][3]);
        wiss4(axh, axl, 0 * 8 + kq * 4, 16384,
              wph[0][0], wph[0][1], wph[0][2], wph[0][3],
              wpl[0][0], wpl[0][1], wpl[0][2], wpl[0][3]);
        stage_issue(gH0, gL0, 1, tid, sr[1][0], sr[1][1], sr[1][2], sr[1][3]);
        wiss4(axh, axl, 1 * 8 + kq * 4, 16384,
              wph[1][0], wph[1][1], wph[1][2], wph[1][3],
              wpl[1][0], wpl[1][1], wpl[1][2], wpl[1][3]);
        #pragma unroll
        for (int ph = 0; ph < 8; ++ph) {
          if (ph < 7) { VM_WAIT(20); } else { VM_WAIT(8); }
          stage_write(&HSH[ph & 1][0], &HSL[ph & 1][0], tid,
                      sr[ph & 1][0], sr[ph & 1][1], sr[ph & 1][2], sr[ph & 1][3]);
          lds_barrier();
          if (ph < 6) {   // stage quarter ph+2 into the set just committed
            const int p2 = ph + 2, hf = p2 >> 2, q2 = p2 & 3;
            stage_issue(hf ? gH1 : gH0, hf ? gL1 : gL0, q2, tid,
                        sr[ph & 1][0], sr[ph & 1][1], sr[ph & 1][2], sr[ph & 1][3]);
          }
          if (ph < 6)      { VM_WAIT(16); }
          else if (ph == 6){ VM_WAIT(12); }
          else             { VM_WAIT(0);  }
          #pragma unroll
          for (int k2 = 0; k2 < 4; ++k2) {
            const int kl = kq * 4 + k2;
            short8 ah = __builtin_bit_cast(short8, wph[ph & 1][k2]);
            short8 al = __builtin_bit_cast(short8, wpl[ph & 1][k2]);
            short8 bh = HSH[ph & 1][bcol * 33 + kl * 4 + quad];
            short8 bl = HSL[ph & 1][bcol * 33 + kl * 4 + quad];
            acc = MFMA(ah, bh, acc);
            acc = MFMA(ah, bl, acc);
            acc = MFMA(al, bh, acc);
          }
          if (ph < 6) {   // weights for phase ph+2 into the consumed set
            const int p2 = ph + 2, hf = p2 >> 2, q2 = p2 & 3;
            wiss4(hf ? ahh : axh, hf ? ahl : axl, q2 * 8 + kq * 4, 16384,
                  wph[ph & 1][0], wph[ph & 1][1], wph[ph & 1][2], wph[ph & 1][3],
                  wpl[ph & 1][0], wpl[ph & 1][1], wpl[ph & 1][2], wpl[ph & 1][3]);
          }
        }
        #pragma unroll
        for (int r = 0; r < 4; ++r)
          gx[(kq * 32 + mt * 16 + quad * 4 + r) * 32 + bcol] = acc[r];
        lds_barrier();
        if (tid < 256) {
          const int u = tid >> 5, b = tid & 31;
          const int j2 = (blk - B0) * 8 + u;
          float gt0 = gx[(0 * 8 + u) * 32 + b] + gx[(32 + 0 * 8 + u) * 32 + b] + bB0;
          float gt1 = gx[(1 * 8 + u) * 32 + b] + gx[(32 + 1 * 8 + u) * 32 + b] + bB1;
          float gt2 = gx[(2 * 8 + u) * 32 + b] + gx[(32 + 2 * 8 + u) * 32 + b] + bB2;
          float gt3 = gx[(3 * 8 + u) * 32 + b] + gx[(32 + 3 * 8 + u) * 32 + b] + bB3;
          float cc = sigmoidf_(gt1) * c1r + sigmoidf_(gt0) * tanhf(gt2);
          float hh = sigmoidf_(gt3) * tanhf(cc);
          c1r = cc;
          unsigned h_, l_;
          bf16split(hh, h_, l_);
          const int wpar = s & 1;
          coh_store_u16(h1h + wpar * 32768 + b * 1024 + j2, h_);
          coh_store_u16(h1l + wpar * 32768 + b * 1024 + j2, l_);
        }
      }
    } else {
      // ---------------- C: vocab projection, s = t-2 --------------------
      const int s = t - 2;
      if (s >= 0 && s < kS) {
        const int kq = w >> 1, nt = w & 1;
        const int growC = (blk - C0) * 16 + m;
        const int bcol = nt * 16 + m;
        const short8* aph = wyh + quad * 256 + growC;
        const short8* apl = wyl + quad * 256 + growC;
        const int rpar = s & 1;
        const unsigned short* gH = h1h + rpar * 32768;
        const unsigned short* gL = h1l + rpar * 32768;
        f32x4 acc = {0.f, 0.f, 0.f, 0.f};
        float4 sr[2][4];
        float4 wph[2][2], wpl[2][2];
        // prologue queue: [s0, w0(4), s1, w1(4)]
        stage_issue(gH, gL, 0, tid, sr[0][0], sr[0][1], sr[0][2], sr[0][3]);
        wiss2(aph, apl, 0 * 8 + kq * 2, 1024, wph[0][0], wph[0][1], wpl[0][0], wpl[0][1]);
        stage_issue(gH, gL, 1, tid, sr[1][0], sr[1][1], sr[1][2], sr[1][3]);
        wiss2(aph, apl, 1 * 8 + kq * 2, 1024, wph[1][0], wph[1][1], wpl[1][0], wpl[1][1]);
        #pragma unroll
        for (int q = 0; q < 4; ++q) {
          if (q < 3) { VM_WAIT(12); } else { VM_WAIT(4); }
          stage_write(&HSH[q & 1][0], &HSL[q & 1][0], tid,
                      sr[q & 1][0], sr[q & 1][1], sr[q & 1][2], sr[q & 1][3]);
          lds_barrier();
          if (q < 2)
            stage_issue(gH, gL, q + 2, tid,
                        sr[q & 1][0], sr[q & 1][1], sr[q & 1][2], sr[q & 1][3]);
          if (q < 2)      { VM_WAIT(12); }
          else if (q == 2){ VM_WAIT(8);  }
          else            { VM_WAIT(0);  }
          #pragma unroll
          for (int k2 = 0; k2 < 2; ++k2) {
            const int kl = kq * 2 + k2;
            short8 ah = __builtin_bit_cast(short8, wph[q & 1][k2]);
            short8 al = __builtin_bit_cast(short8, wpl[q & 1][k2]);
            short8 bh = HSH[q & 1][bcol * 33 + kl * 4 + quad];
            short8 bl = HSL[q & 1][bcol * 33 + kl * 4 + quad];
            acc = MFMA(ah, bh, acc);
            acc = MFMA(ah, bl, acc);
            acc = MFMA(al, bh, acc);
          }
          if (q < 2)
            wiss2(aph, apl, (q + 2) * 8 + kq * 2, 1024,
                  wph[q & 1][0], wph[q & 1][1], wpl[q & 1][0], wpl[q & 1][1]);
        }
        #pragma unroll
        for (int r = 0; r < 4; ++r)
          gx[(kq * 16 + quad * 4 + r) * 32 + bcol] = acc[r];
        lds_barrier();
        {
          const int b = tid >> 4, vl = tid & 15;
          const int vg = (blk - C0) * 16 + vl;
          float sum = gx[(0 * 16 + vl) * 32 + b] + gx[(1 * 16 + vl) * 32 + b] +
                      gx[(2 * 16 + vl) * 32 + b] + gx[(3 * 16 + vl) * 32 + b];
          out[(s * kB + b) * kV + vg] = sum + byr;
        }
      }
    }

    // ---------------- flag barrier (contention-free, from R4) ------------
    if (t < kS + 1) {
      __syncthreads();                         // drains vmcnt per wave
      const unsigned target = (unsigned)(t + 1);
      if (tid == 0) coh_store_u32(arrive + blk * 16, target);
      if (blk == ROOT) {
        if (tid < 64) {
          const unsigned* q0 = arrive + tid * 16;
          const unsigned* q1 = arrive + (64 + tid) * 16;
          const unsigned* q2 = arrive + (128 + tid) * 16;
          const int i3 = (192 + tid < NBLK) ? (192 + tid) : 0;
          const unsigned* q3 = arrive + i3 * 16;
          int guard = 0;
          for (;;) {
            unsigned a, b, c, d;
            asm volatile(
                "global_load_dword %0, %4, off sc0 sc1\n\t"
                "global_load_dword %1, %5, off sc0 sc1\n\t"
                "global_load_dword %2, %6, off sc0 sc1\n\t"
                "global_load_dword %3, %7, off sc0 sc1\n\t"
                "s_waitcnt vmcnt(0)"
                : "=&v"(a), "=&v"(b), "=&v"(c), "=&v"(d)
                : "v"(q0), "v"(q1), "v"(q2), "v"(q3) : "memory");
            bool ok = (a >= target) && (b >= target) && (c >= target) && (d >= target);
            if (__all(ok)) break;
            if (++guard > (1 << 17)) break;    // anti-hang valve
          }
          if (tid == 0) coh_store_u32(gen, target);
        }
      } else {
        if (tid == 0) {
          int guard = 0;
          while (coh_load_u32(gen) < target) {
            __builtin_amdgcn_s_sleep(1);
            if (++guard > (1 << 17)) break;    // anti-hang valve
          }
        }
      }
      __syncthreads();
    }
  }
}

// -------------------------- host launcher ----------------------------------

extern "C" void kernel_launch(void* const* d_in, const int* in_sizes, int n_in,
                              void* d_out, int out_size, void* d_ws, size_t ws_size,
                              hipStream_t stream) {
  const int*   x   = (const int*)d_in[0];
  const float* Wx0 = (const float*)d_in[1];
  const float* Wh0 = (const float*)d_in[2];
  const float* b0v = (const float*)d_in[3];
  const float* Wx1 = (const float*)d_in[4];
  const float* Wh1 = (const float*)d_in[5];
  const float* b1v = (const float*)d_in[6];
  const float* Why = (const float*)d_in[7];
  const float* byv = (const float*)d_in[8];
  unsigned short* wss = (unsigned short*)d_ws;
  float* outp = (float*)d_out;

  hipLaunchKernelGGL(pack_w, dim3(2048), dim3(256), 0, stream,
                     Wh0, wss + WP0H, wss + WP0L, G4H);
  hipLaunchKernelGGL(pack_w, dim3(2048), dim3(256), 0, stream,
                     Wx1, wss + WP1XH, wss + WP1XL, G4H);
  hipLaunchKernelGGL(pack_w, dim3(2048), dim3(256), 0, stream,
                     Wh1, wss + WP1HH, wss + WP1HL, G4H);
  hipLaunchKernelGGL(pack_w, dim3(128), dim3(256), 0, stream,
                     Why, wss + WYH, wss + WYL, kV);
  // zero h arrays (262144 shorts = 131072 u32) + flags/gen (4097 u32)
  hipLaunchKernelGGL(zero_state, dim3(529), dim3(256), 0, stream,
                     (unsigned*)(wss + HOFF), 131072 + 4100);

  hipLaunchKernelGGL(lstm_persist, dim3(NBLK), dim3(NT), 0, stream,
                     x, Wx0, b0v, b1v, byv, wss, outp);
}

// Round 4
// 8740.919 us; speedup vs baseline: 1.2747x; 1.2747x over previous
//
#include <hip/hip_runtime.h>
#include <math.h>

// ---------------------------------------------------------------------------
// Persistent 2-layer LSTM via MFMA split-bf16 (hi+lo, 3-term) fp32 emulation.
// 208 blocks x 512 thr (1/CU). Pipeline: A(64)=layer0 s=t | B(128)=layer1
// s=t-1 | C(16)=proj s=t-2. R4 flag barrier.
// R10: revert to R6's proven schedule (stage -> vmcnt(0) -> sync -> compiler-
// scheduled weight loads + MFMA -> sync); async prefetch removed (R7/R9 both
// regressed ~40%, doubled FETCH). Change vs R6: stage 512-k HALVES instead of
// 256-k quarters -> half the serial stall points (B: 8->4, A/C: 4->2), 8 loads
// in flight per stage, 16-deep kl loop gives compiler more overlap room.
// Biases hoisted; A's Wx0 epilogue gather issued early via plain loads.
// ---------------------------------------------------------------------------

typedef __attribute__((ext_vector_type(8))) short short8;
typedef __attribute__((ext_vector_type(4))) float f32x4;

constexpr int kV = 256, kH = 1024, kB = 32, kS = 512, G4H = 4096;
constexpr int NT = 512, NBLK = 208;
constexpr int NA = 64, B0 = 64, C0 = 192, ROOT = NBLK - 1;

// ws layout in SHORT units
constexpr long SZW = 4194304L;            // shorts per packed 1024x4096 matrix
constexpr long SZY = 262144L;             // shorts per packed Why array
constexpr long WP0H = 0,        WP0L = SZW;
constexpr long WP1XH = 2*SZW,   WP1XL = 3*SZW;
constexpr long WP1HH = 4*SZW,   WP1HL = 5*SZW;
constexpr long WYH  = 6*SZW,    WYL  = 6*SZW + SZY;
constexpr long HOFF = 6*SZW + 2*SZY;      // h arrays: h0h[2][32K],h0l,h1h,h1l

#define MFMA(a,b,c) __builtin_amdgcn_mfma_f32_16x16x32_bf16(a, b, c, 0, 0, 0)

__device__ __forceinline__ float sigmoidf_(float v) { return 1.f / (1.f + expf(-v)); }

__device__ __forceinline__ void bf16split(float w, unsigned& hi, unsigned& lo) {
  unsigned u = __float_as_uint(w);
  unsigned r = (u + 0x7fffu + ((u >> 16) & 1u)) >> 16;
  float res = w - __uint_as_float(r << 16);
  unsigned u2 = __float_as_uint(res);
  unsigned r2 = (u2 + 0x7fffu + ((u2 >> 16) & 1u)) >> 16;
  hi = r; lo = r2;
}

// ---------------- coherent (cache-bypass) helpers --------------------------

__device__ __forceinline__ void coh_store_u32(unsigned* p, unsigned v) {
  asm volatile("global_store_dword %0, %1, off sc0 sc1" :: "v"(p), "v"(v) : "memory");
}
__device__ __forceinline__ void coh_store_u16(unsigned short* p, unsigned v) {
  asm volatile("global_store_short %0, %1, off sc0 sc1" :: "v"(p), "v"(v) : "memory");
}
__device__ __forceinline__ unsigned coh_load_u32(const unsigned* p) {
  unsigned v;
  asm volatile("global_load_dword %0, %1, off sc0 sc1\n\ts_waitcnt vmcnt(0)"
               : "=v"(v) : "v"(p) : "memory");
  return v;
}

// stage one 512-k HALF of h (hi+lo) into LDS; all 512 threads.
// Layout: HH[b*65 + g], g in [0,64): k = half*512 + g*8 .. +8. Row stride 65
// short8 (1040 B = 4 banks offset/row -> same conflict profile as R6's 33).
__device__ __forceinline__ void stage_h8(short8* HH, short8* HL,
                                         const unsigned short* gH,
                                         const unsigned short* gL,
                                         int half, int tid) {
  const int b = tid >> 4, kg = tid & 15;
  const unsigned short* ph = gH + b * 1024 + half * 512 + kg * 8;
  const unsigned short* pl = gL + b * 1024 + half * 512 + kg * 8;
  float4 h0, h1, h2, h3, l0, l1, l2, l3;
  asm volatile(
      "global_load_dwordx4 %0, %8, off sc0 sc1\n\t"
      "global_load_dwordx4 %1, %9, off sc0 sc1\n\t"
      "global_load_dwordx4 %2, %10, off sc0 sc1\n\t"
      "global_load_dwordx4 %3, %11, off sc0 sc1\n\t"
      "global_load_dwordx4 %4, %12, off sc0 sc1\n\t"
      "global_load_dwordx4 %5, %13, off sc0 sc1\n\t"
      "global_load_dwordx4 %6, %14, off sc0 sc1\n\t"
      "global_load_dwordx4 %7, %15, off sc0 sc1\n\t"
      "s_waitcnt vmcnt(0)"
      : "=&v"(h0), "=&v"(h1), "=&v"(h2), "=&v"(h3),
        "=&v"(l0), "=&v"(l1), "=&v"(l2), "=&v"(l3)
      : "v"(ph), "v"(ph + 128), "v"(ph + 256), "v"(ph + 384),
        "v"(pl), "v"(pl + 128), "v"(pl + 256), "v"(pl + 384)
      : "memory");
  HH[b * 65 + kg +  0] = __builtin_bit_cast(short8, h0);
  HH[b * 65 + kg + 16] = __builtin_bit_cast(short8, h1);
  HH[b * 65 + kg + 32] = __builtin_bit_cast(short8, h2);
  HH[b * 65 + kg + 48] = __builtin_bit_cast(short8, h3);
  HL[b * 65 + kg +  0] = __builtin_bit_cast(short8, l0);
  HL[b * 65 + kg + 16] = __builtin_bit_cast(short8, l1);
  HL[b * 65 + kg + 32] = __builtin_bit_cast(short8, l2);
  HL[b * 65 + kg + 48] = __builtin_bit_cast(short8, l3);
}

// -------------------------- prep kernels -----------------------------------

__global__ void pack_w(const float* __restrict__ in, unsigned short* __restrict__ hi,
                       unsigned short* __restrict__ lo, int ncols) {
  int id = blockIdx.x * 256 + threadIdx.x;
  int slab = id / ncols, row = id % ncols;   // slab < 128
  int k0 = (slab >> 2) * 32 + (slab & 3) * 8;
  long ob = ((long)slab * ncols + row) * 8;
  #pragma unroll
  for (int e = 0; e < 8; ++e) {
    float w = in[(long)(k0 + e) * ncols + row];
    unsigned h_, l_;
    bf16split(w, h_, l_);
    hi[ob + e] = (unsigned short)h_;
    lo[ob + e] = (unsigned short)l_;
  }
}

__global__ void zero_state(unsigned* __restrict__ p, int n) {
  int i = blockIdx.x * 256 + threadIdx.x;
  if (i < n) p[i] = 0u;
}

// -------------------------- main persistent kernel -------------------------

extern "C" __global__ void __launch_bounds__(512, 1)
lstm_persist(const int* __restrict__ x,
             const float* __restrict__ Wx0,
             const float* __restrict__ b0v,
             const float* __restrict__ b1v,
             const float* __restrict__ byv,
             unsigned short* __restrict__ wss,
             float* __restrict__ out) {
  const short8* wp0h  = (const short8*)(wss + WP0H);
  const short8* wp0l  = (const short8*)(wss + WP0L);
  const short8* wp1xh = (const short8*)(wss + WP1XH);
  const short8* wp1xl = (const short8*)(wss + WP1XL);
  const short8* wp1hh = (const short8*)(wss + WP1HH);
  const short8* wp1hl = (const short8*)(wss + WP1HL);
  const short8* wyh   = (const short8*)(wss + WYH);
  const short8* wyl   = (const short8*)(wss + WYL);
  unsigned short* h0h = wss + HOFF;            // [2][32][1024]
  unsigned short* h0l = h0h + 65536;
  unsigned short* h1h = h0h + 131072;
  unsigned short* h1l = h0h + 196608;
  unsigned* arrive = (unsigned*)(h0h + 262144);  // stride-16 flags
  unsigned* gen = arrive + 4096;

  const int tid = threadIdx.x, blk = blockIdx.x;
  const int lane = tid & 63, m = lane & 15, quad = lane >> 4, w = tid >> 6;

  __shared__ short8 HSH[32 * 65];   // 32.5 KB  h hi half
  __shared__ short8 HSL[32 * 65];   // 32.5 KB  h lo half
  __shared__ float gx[2048];        // 8 KB gate/output exchange

  float c0r = 0.f, c1r = 0.f;

  // ---- loop-invariant bias loads (hoisted out of the t-loop) --------------
  float bA0 = 0.f, bA1 = 0.f, bA2 = 0.f, bA3 = 0.f;
  float bB0 = 0.f, bB1 = 0.f, bB2 = 0.f, bB3 = 0.f;
  float byr = 0.f;
  if (blk < NA) {
    const int u = tid >> 5, j2e = blk * 16 + u;
    bA0 = b0v[j2e];            bA1 = b0v[kH + j2e];
    bA2 = b0v[2 * kH + j2e];   bA3 = b0v[3 * kH + j2e];
  } else if (blk < C0) {
    if (tid < 256) {
      const int u = tid >> 5, j2e = (blk - B0) * 8 + u;
      bB0 = b1v[j2e];          bB1 = b1v[kH + j2e];
      bB2 = b1v[2 * kH + j2e]; bB3 = b1v[3 * kH + j2e];
    }
  } else {
    byr = byv[(blk - C0) * 16 + (tid & 15)];
  }

  #pragma unroll 1
  for (int t = 0; t < kS + 2; ++t) {
    if (blk < NA) {
      // ---------------- A: layer0 cell, s = t ---------------------------
      const int s = t;
      if (s < kS) {
        const int g = w >> 1, nt = w & 1, j0A = blk * 16;
        const int bcol = nt * 16 + m;
        const short8* aph = wp0h + quad * 4096 + (g * 1024 + j0A + m);
        const short8* apl = wp0l + quad * 4096 + (g * 1024 + j0A + m);
        const int rpar = (s + 1) & 1;
        const unsigned short* gH = h0h + rpar * 32768;
        const unsigned short* gL = h0l + rpar * 32768;
        // early epilogue operands (plain loads; complete during the rounds)
        const int ue = tid >> 5, be = tid & 31, j2e = j0A + ue;
        const int xs = x[be * kS + s];
        const float* wxp = Wx0 + (long)xs * G4H + j2e;
        const float wxi = wxp[0], wxf = wxp[kH];
        const float wxg = wxp[2 * kH], wxo = wxp[3 * kH];
        f32x4 acc = {0.f, 0.f, 0.f, 0.f};
        #pragma unroll 1
        for (int r = 0; r < 2; ++r) {
          stage_h8(HSH, HSL, gH, gL, r, tid);
          __syncthreads();
          #pragma unroll
          for (int kl = 0; kl < 16; ++kl) {
            const int kk = r * 16 + kl;
            short8 ah = aph[kk * 16384];
            short8 al = apl[kk * 16384];
            short8 bh = HSH[bcol * 65 + kl * 4 + quad];
            short8 bl = HSL[bcol * 65 + kl * 4 + quad];
            acc = MFMA(ah, bh, acc);
            acc = MFMA(ah, bl, acc);
            acc = MFMA(al, bh, acc);
          }
          __syncthreads();
        }
        #pragma unroll
        for (int r = 0; r < 4; ++r)
          gx[(g * 16 + quad * 4 + r) * 32 + bcol] = acc[r];
        __syncthreads();
        {
          float gi = gx[(0 * 16 + ue) * 32 + be] + wxi + bA0;
          float gf = gx[(1 * 16 + ue) * 32 + be] + wxf + bA1;
          float gg = gx[(2 * 16 + ue) * 32 + be] + wxg + bA2;
          float go = gx[(3 * 16 + ue) * 32 + be] + wxo + bA3;
          float cc = sigmoidf_(gf) * c0r + sigmoidf_(gi) * tanhf(gg);
          float hh = sigmoidf_(go) * tanhf(cc);
          c0r = cc;
          unsigned h_, l_;
          bf16split(hh, h_, l_);
          const int wpar = s & 1;
          coh_store_u16(h0h + wpar * 32768 + be * 1024 + j2e, h_);
          coh_store_u16(h0l + wpar * 32768 + be * 1024 + j2e, l_);
        }
      }
    } else if (blk < C0) {
      // ---------------- B: layer1 cell, s = t-1 -------------------------
      const int s = t - 1;
      if (s >= 0 && s < kS) {
        const int kq = w >> 2, mt = (w >> 1) & 1, nt = w & 1;
        const int rowB = mt * 16 + m;
        const int gB = rowB >> 3, uB = rowB & 7;
        const int growB = gB * 1024 + (blk - B0) * 8 + uB;
        const int bcol = nt * 16 + m;
        f32x4 acc = {0.f, 0.f, 0.f, 0.f};
        #pragma unroll 1
        for (int r = 0; r < 4; ++r) {
          const int hf = r >> 1, rr = r & 1;
          const int rpar = hf ? ((s + 1) & 1) : (s & 1);
          const unsigned short* gH = (hf ? h1h : h0h) + rpar * 32768;
          const unsigned short* gL = (hf ? h1l : h0l) + rpar * 32768;
          const short8* aph = (hf ? wp1hh : wp1xh) + quad * 4096 + growB;
          const short8* apl = (hf ? wp1hl : wp1xl) + quad * 4096 + growB;
          stage_h8(HSH, HSL, gH, gL, rr, tid);
          __syncthreads();
          #pragma unroll
          for (int k2 = 0; k2 < 8; ++k2) {
            const int kl = kq * 8 + k2;
            const int kk = rr * 16 + kl;
            short8 ah = aph[kk * 16384];
            short8 al = apl[kk * 16384];
            short8 bh = HSH[bcol * 65 + kl * 4 + quad];
            short8 bl = HSL[bcol * 65 + kl * 4 + quad];
            acc = MFMA(ah, bh, acc);
            acc = MFMA(ah, bl, acc);
            acc = MFMA(al, bh, acc);
          }
          __syncthreads();
        }
        #pragma unroll
        for (int r = 0; r < 4; ++r)
          gx[(kq * 32 + mt * 16 + quad * 4 + r) * 32 + bcol] = acc[r];
        __syncthreads();
        if (tid < 256) {
          const int u = tid >> 5, b = tid & 31;
          const int j2 = (blk - B0) * 8 + u;
          float gt0 = gx[(0 * 8 + u) * 32 + b] + gx[(32 + 0 * 8 + u) * 32 + b] + bB0;
          float gt1 = gx[(1 * 8 + u) * 32 + b] + gx[(32 + 1 * 8 + u) * 32 + b] + bB1;
          float gt2 = gx[(2 * 8 + u) * 32 + b] + gx[(32 + 2 * 8 + u) * 32 + b] + bB2;
          float gt3 = gx[(3 * 8 + u) * 32 + b] + gx[(32 + 3 * 8 + u) * 32 + b] + bB3;
          float cc = sigmoidf_(gt1) * c1r + sigmoidf_(gt0) * tanhf(gt2);
          float hh = sigmoidf_(gt3) * tanhf(cc);
          c1r = cc;
          unsigned h_, l_;
          bf16split(hh, h_, l_);
          const int wpar = s & 1;
          coh_store_u16(h1h + wpar * 32768 + b * 1024 + j2, h_);
          coh_store_u16(h1l + wpar * 32768 + b * 1024 + j2, l_);
        }
      }
    } else {
      // ---------------- C: vocab projection, s = t-2 --------------------
      const int s = t - 2;
      if (s >= 0 && s < kS) {
        const int kq = w >> 1, nt = w & 1;
        const int growC = (blk - C0) * 16 + m;
        const int bcol = nt * 16 + m;
        const short8* aph = wyh + quad * 256 + growC;
        const short8* apl = wyl + quad * 256 + growC;
        const int rpar = s & 1;
        const unsigned short* gH = h1h + rpar * 32768;
        const unsigned short* gL = h1l + rpar * 32768;
        f32x4 acc = {0.f, 0.f, 0.f, 0.f};
        #pragma unroll 1
        for (int r = 0; r < 2; ++r) {
          stage_h8(HSH, HSL, gH, gL, r, tid);
          __syncthreads();
          #pragma unroll
          for (int k2 = 0; k2 < 4; ++k2) {
            const int kl = kq * 4 + k2;
            const int kk = r * 16 + kl;
            short8 ah = aph[kk * 1024];
            short8 al = apl[kk * 1024];
            short8 bh = HSH[bcol * 65 + kl * 4 + quad];
            short8 bl = HSL[bcol * 65 + kl * 4 + quad];
            acc = MFMA(ah, bh, acc);
            acc = MFMA(ah, bl, acc);
            acc = MFMA(al, bh, acc);
          }
          __syncthreads();
        }
        #pragma unroll
        for (int r = 0; r < 4; ++r)
          gx[(kq * 16 + quad * 4 + r) * 32 + bcol] = acc[r];
        __syncthreads();
        {
          const int b = tid >> 4, vl = tid & 15;
          const int vg = (blk - C0) * 16 + vl;
          float sum = gx[(0 * 16 + vl) * 32 + b] + gx[(1 * 16 + vl) * 32 + b] +
                      gx[(2 * 16 + vl) * 32 + b] + gx[(3 * 16 + vl) * 32 + b];
          out[(s * kB + b) * kV + vg] = sum + byr;
        }
      }
    }

    // ---------------- flag barrier (contention-free, from R4) ------------
    if (t < kS + 1) {
      __syncthreads();                         // drains vmcnt per wave
      const unsigned target = (unsigned)(t + 1);
      if (tid == 0) coh_store_u32(arrive + blk * 16, target);
      if (blk == ROOT) {
        if (tid < 64) {
          const unsigned* q0 = arrive + tid * 16;
          const unsigned* q1 = arrive + (64 + tid) * 16;
          const unsigned* q2 = arrive + (128 + tid) * 16;
          const int i3 = (192 + tid < NBLK) ? (192 + tid) : 0;
          const unsigned* q3 = arrive + i3 * 16;
          int guard = 0;
          for (;;) {
            unsigned a, b, c, d;
            asm volatile(
                "global_load_dword %0, %4, off sc0 sc1\n\t"
                "global_load_dword %1, %5, off sc0 sc1\n\t"
                "global_load_dword %2, %6, off sc0 sc1\n\t"
                "global_load_dword %3, %7, off sc0 sc1\n\t"
                "s_waitcnt vmcnt(0)"
                : "=&v"(a), "=&v"(b), "=&v"(c), "=&v"(d)
                : "v"(q0), "v"(q1), "v"(q2), "v"(q3) : "memory");
            bool ok = (a >= target) && (b >= target) && (c >= target) && (d >= target);
            if (__all(ok)) break;
            if (++guard > (1 << 17)) break;    // anti-hang valve
          }
          if (tid == 0) coh_store_u32(gen, target);
        }
      } else {
        if (tid == 0) {
          int guard = 0;
          while (coh_load_u32(gen) < target) {
            __builtin_amdgcn_s_sleep(1);
            if (++guard > (1 << 17)) break;    // anti-hang valve
          }
        }
      }
      __syncthreads();
    }
  }
}

// -------------------------- host launcher ----------------------------------

extern "C" void kernel_launch(void* const* d_in, const int* in_sizes, int n_in,
                              void* d_out, int out_size, void* d_ws, size_t ws_size,
                              hipStream_t stream) {
  const int*   x   = (const int*)d_in[0];
  const float* Wx0 = (const float*)d_in[1];
  const float* Wh0 = (const float*)d_in[2];
  const float* b0v = (const float*)d_in[3];
  const float* Wx1 = (const float*)d_in[4];
  const float* Wh1 = (const float*)d_in[5];
  const float* b1v = (const float*)d_in[6];
  const float* Why = (const float*)d_in[7];
  const float* byv = (const float*)d_in[8];
  unsigned short* wss = (unsigned short*)d_ws;
  float* outp = (float*)d_out;

  hipLaunchKernelGGL(pack_w, dim3(2048), dim3(256), 0, stream,
                     Wh0, wss + WP0H, wss + WP0L, G4H);
  hipLaunchKernelGGL(pack_w, dim3(2048), dim3(256), 0, stream,
                     Wx1, wss + WP1XH, wss + WP1XL, G4H);
  hipLaunchKernelGGL(pack_w, dim3(2048), dim3(256), 0, stream,
                     Wh1, wss + WP1HH, wss + WP1HL, G4H);
  hipLaunchKernelGGL(pack_w, dim3(128), dim3(256), 0, stream,
                     Why, wss + WYH, wss + WYL, kV);
  // zero h arrays (262144 shorts = 131072 u32) + flags/gen (4097 u32)
  hipLaunchKernelGGL(zero_state, dim3(529), dim3(256), 0, stream,
                     (unsigned*)(wss + HOFF), 131072 + 4100);

  hipLaunchKernelGGL(lstm_persist, dim3(NBLK), dim3(NT), 0, stream,
                     x, Wx0, b0v, b1v, byv, wss, outp);
}